// Round 14
// baseline (426.128 us; speedup 1.0000x reference)
//
#include <hip/hip_runtime.h>
#include <hip/hip_bf16.h>

#define NROWS 131072
#define DDIM  256
#define CDIM  1024

#define L2E 1.4426950408889634f
#define LN2 0.6931471805599453f

typedef short bf16x8 __attribute__((ext_vector_type(8)));
typedef float f32x4 __attribute__((ext_vector_type(4)));

#define GLOAD_LDS16(g, l) __builtin_amdgcn_global_load_lds( \
    (const __attribute__((address_space(1))) void*)(g),      \
    (__attribute__((address_space(3))) void*)(l), 16, 0, 0)

__device__ __forceinline__ unsigned short f2b(float x) {
    unsigned int u = __builtin_bit_cast(unsigned int, x);
    u = (u + 0x7FFFu + ((u >> 16) & 1u)) >> 16;   // round-to-nearest-even
    return (unsigned short)u;
}

// ---------------- 1a) label histogram: grid-parallel global atomics ---------
__global__ void k_hist(const int* __restrict__ labels, int* __restrict__ hist) {
    const int i = blockIdx.x * 256 + threadIdx.x;
    atomicAdd(&hist[labels[i]], 1);
}

// ---------------- 1b) exclusive scan over 1024 counts; zero out accumulator -
__global__ void k_scan(const int* __restrict__ hist, int* __restrict__ offsets,
                       float* __restrict__ out) {
    __shared__ int tmp[CDIM];
    const int t = threadIdx.x;
    const int v = hist[t];
    tmp[t] = v;
    __syncthreads();
    for (int d = 1; d < CDIM; d <<= 1) {
        const int add = (t >= d) ? tmp[t - d] : 0;
        __syncthreads();
        tmp[t] += add;
        __syncthreads();
    }
    offsets[t] = tmp[t] - v;
    if (t == CDIM - 1) offsets[CDIM] = tmp[t];
    if (t == 0) out[0] = 0.0f;
}

// ---------------- 1c) scatter row indices into label-grouped order ----------
__global__ void k_scatter(const int* __restrict__ labels, const int* __restrict__ offsets,
                          int* __restrict__ cursor, int* __restrict__ rowidx) {
    const int i = blockIdx.x * 256 + threadIdx.x;
    const int lab = labels[i];
    const int pos = atomicAdd(&cursor[lab], 1);
    rowidx[offsets[lab] + pos] = i;
}

// ---------------- 2) centroid gather -> bf16 in MFMA-granule order ----------
// granule (cc,ct,kk,lane): 16B = cent[col=cc*64+ct*16+lr][k=kk*32+lg*8 ..+8]
// halfword index = cc*16384 + ct*4096 + kk*512 + lane*8
__global__ void k_centroid(const float* __restrict__ emb, const int* __restrict__ rowidx,
                           const int* __restrict__ offsets, unsigned short* __restrict__ centG) {
    __shared__ int ridx[256];
    __shared__ f32x4 red[4][64];
    const int cgrp = blockIdx.x;
    const int t = threadIdx.x;
    const int w = t >> 6;
    const int lane = t & 63;
    const int beg = offsets[cgrp], end = offsets[cgrp + 1];

    f32x4 acc = {0.0f, 0.0f, 0.0f, 0.0f};
    for (int base = beg; base < end; base += 256) {
        const int cnt = min(256, end - base);
        __syncthreads();
        if (t < cnt) ridx[t] = rowidx[base + t];
        __syncthreads();
        // 4 rows in flight per wave (VMEM ILP=4)
        for (int i = w * 4; i < cnt; i += 16) {
            float4 v[4];
            int nr = min(4, cnt - i);
#pragma unroll
            for (int j = 0; j < 4; ++j) {
                if (j < nr) {
                    const int row = ridx[i + j];
                    v[j] = *reinterpret_cast<const float4*>(emb + (size_t)row * DDIM + lane * 4);
                } else {
                    v[j] = make_float4(0.f, 0.f, 0.f, 0.f);
                }
            }
#pragma unroll
            for (int j = 0; j < 4; ++j) {
                acc[0] += v[j].x; acc[1] += v[j].y; acc[2] += v[j].z; acc[3] += v[j].w;
            }
        }
    }
    red[w][lane] = acc;
    __syncthreads();
    if (t < 32) {
        const float inv = 1.0f / (float)(end - beg);
        f32x4 a = red[0][2 * t], b4 = red[0][2 * t + 1];
#pragma unroll
        for (int ww = 1; ww < 4; ++ww) {
            const f32x4 x = red[ww][2 * t], y = red[ww][2 * t + 1];
            a[0] += x[0]; a[1] += x[1]; a[2] += x[2]; a[3] += x[3];
            b4[0] += y[0]; b4[1] += y[1]; b4[2] += y[2]; b4[3] += y[3];
        }
        uint4 u;
        u.x = (unsigned)f2b(a[0] * inv) | ((unsigned)f2b(a[1] * inv) << 16);
        u.y = (unsigned)f2b(a[2] * inv) | ((unsigned)f2b(a[3] * inv) << 16);
        u.z = (unsigned)f2b(b4[0] * inv) | ((unsigned)f2b(b4[1] * inv) << 16);
        u.w = (unsigned)f2b(b4[2] * inv) | ((unsigned)f2b(b4[3] * inv) << 16);
        const int cc = cgrp >> 6, ctq = (cgrp >> 4) & 3, lr2 = cgrp & 15;
        const int kk = t >> 2, lg2 = t & 3;
        *reinterpret_cast<uint4*>(centG + (size_t)cc * 16384 + ctq * 4096 + kk * 512
                                  + (lg2 * 16 + lr2) * 8) = u;
    }
}

// ---------------- 3) fused GEMM + online softmax + NLL ----------------
// BM=256, 512 thr (8 waves). Each wave owns 32 rows = 2 A-fragment sets (M_rep=2):
// every B fragment read from LDS feeds 2 MFMAs (halves B-LDS traffic vs M_rep=1).
// LDS = B double-buffer (2 x 32KB). Counted-drain barriers as before.
__launch_bounds__(512, 3)
__global__ void k_logits(const float* __restrict__ emb, const int* __restrict__ labels,
                         const unsigned short* __restrict__ centG, const float* __restrict__ wp,
                         float* __restrict__ out) {
    __shared__ unsigned short lds[2][16384];   // 2 x 32 KB

    const float wl2e = wp[0] * L2E;            // fold w and 1/ln2 into one scale
    const int t = threadIdx.x;
    const int w = t >> 6;                      // 0..7
    const int lane = t & 63;
    const int lg = lane >> 4;
    const int lr = lane & 15;
    const int rowbase = blockIdx.x * 256;

    // ---- issue B chunk-0 DMA -> lds[1]: 8 waves x 4 x 1KB ----
#pragma unroll
    for (int j = 0; j < 4; ++j) {
        const int J = w * 4 + j;
        GLOAD_LDS16(centG + J * 512 + lane * 8, &lds[1][J * 512]);
    }
    __builtin_amdgcn_sched_barrier(0);

    // ---- A fragments direct from global: af[mr][kk], rows w*32+mr*16+lr ----
    bf16x8 af[2][8];
#pragma unroll
    for (int mr = 0; mr < 2; ++mr) {
        const int myrow = rowbase + w * 32 + mr * 16 + lr;
#pragma unroll
        for (int kk = 0; kk < 8; ++kk) {
            const float* src = emb + (size_t)myrow * DDIM + kk * 32 + lg * 8;
            const float4 a0 = *reinterpret_cast<const float4*>(src);
            const float4 a1 = *reinterpret_cast<const float4*>(src + 4);
            bf16x8 f;
            f[0] = (short)f2b(a0.x); f[1] = (short)f2b(a0.y);
            f[2] = (short)f2b(a0.z); f[3] = (short)f2b(a0.w);
            f[4] = (short)f2b(a1.x); f[5] = (short)f2b(a1.y);
            f[6] = (short)f2b(a1.z); f[7] = (short)f2b(a1.w);
            af[mr][kk] = f;
        }
    }

    // ---- per-lane online state (log2 domain); output row = w*32+mr*16+lg*4+r ----
    float m[2][4], s[2][4], lv[2][4];
    int labs[2][4];
#pragma unroll
    for (int mr = 0; mr < 2; ++mr)
#pragma unroll
        for (int r = 0; r < 4; ++r) {
            m[mr][r] = -1e30f; s[mr][r] = 0.0f; lv[mr][r] = 0.0f;
            labs[mr][r] = labels[rowbase + w * 32 + mr * 16 + lg * 4 + r];
        }

    asm volatile("s_waitcnt vmcnt(0)" ::: "memory");
    __builtin_amdgcn_s_barrier();

    for (int cc = 0; cc < 16; ++cc) {
        if (cc < 15) {
            const unsigned short* src = centG + (cc + 1) * 16384;
#pragma unroll
            for (int j = 0; j < 4; ++j) {
                const int J = w * 4 + j;
                GLOAD_LDS16(src + J * 512 + lane * 8, &lds[cc & 1][J * 512]);
            }
            __builtin_amdgcn_sched_barrier(0);
        }
        const unsigned short* bb = &lds[(cc + 1) & 1][lane * 8];
        float vals[2][4][4];
#pragma unroll
        for (int ct = 0; ct < 4; ++ct) {
            f32x4 acc0 = {0.0f, 0.0f, 0.0f, 0.0f};
            f32x4 acc1 = {0.0f, 0.0f, 0.0f, 0.0f};
#pragma unroll
            for (int kk = 0; kk < 8; ++kk) {
                const bf16x8 bf = *reinterpret_cast<const bf16x8*>(bb + ct * 4096 + kk * 512);
                acc0 = __builtin_amdgcn_mfma_f32_16x16x32_bf16(af[0][kk], bf, acc0, 0, 0, 0);
                acc1 = __builtin_amdgcn_mfma_f32_16x16x32_bf16(af[1][kk], bf, acc1, 0, 0, 0);
            }
            const int colg = cc * 64 + ct * 16 + lr;
#pragma unroll
            for (int r = 0; r < 4; ++r) {
                const float e0 = wl2e * acc0[r];
                const float e1 = wl2e * acc1[r];
                vals[0][ct][r] = e0;
                vals[1][ct][r] = e1;
                if (colg == labs[0][r]) lv[0][r] = e0;
                if (colg == labs[1][r]) lv[1][r] = e1;
            }
        }
#pragma unroll
        for (int mr = 0; mr < 2; ++mr)
#pragma unroll
            for (int r = 0; r < 4; ++r) {
                const float cmax = fmaxf(fmaxf(fmaxf(vals[mr][0][r], vals[mr][1][r]),
                                               vals[mr][2][r]), vals[mr][3][r]);
                const float mo = m[mr][r];
                const float mn = fmaxf(mo, cmax);
                const float ssum = exp2f(vals[mr][0][r] - mn) + exp2f(vals[mr][1][r] - mn)
                                 + exp2f(vals[mr][2][r] - mn) + exp2f(vals[mr][3][r] - mn);
                s[mr][r] = s[mr][r] * exp2f(mo - mn) + ssum;
                m[mr][r] = mn;
            }
        asm volatile("s_waitcnt vmcnt(0)" ::: "memory");  // own DMA for cc+1 landed
        __builtin_amdgcn_s_barrier();                     // all waves done reading
    }

    // ---- merge 16 lanes per row group; accumulate NLL (log2 units -> *LN2) ----
    float part = 0.0f;
#pragma unroll
    for (int mr = 0; mr < 2; ++mr)
#pragma unroll
        for (int r = 0; r < 4; ++r) {
            float mm = m[mr][r], ss = s[mr][r], ll = lv[mr][r];
#pragma unroll
            for (int off = 1; off < 16; off <<= 1) {
                const float mo = __shfl_xor(mm, off, 64);
                const float so = __shfl_xor(ss, off, 64);
                const float lo = __shfl_xor(ll, off, 64);
                const float mn = fmaxf(mm, mo);
                ss = ss * exp2f(mm - mn) + so * exp2f(mo - mn);
                mm = mn;
                ll += lo;
            }
            if (lr == 0) part += (mm + log2f(ss) - ll);
        }
    if (lr == 0) atomicAdd(out, part * (LN2 / NROWS));
}

extern "C" void kernel_launch(void* const* d_in, const int* in_sizes, int n_in,
                              void* d_out, int out_size, void* d_ws, size_t ws_size,
                              hipStream_t stream) {
    const float* emb = (const float*)d_in[0];
    const int* labels = (const int*)d_in[1];
    const float* wp = (const float*)d_in[2];
    // d_in[3] (b) cancels in the NLL; unused.
    float* out = (float*)d_out;

    // ws byte layout:
    //   0       hist     int[1024]   (4 KB)
    //   4096    cursor   int[1024]   (4 KB)
    //   8192    offsets  int[1025]
    //   16384   rowidx   int[131072] (512 KB)
    //   540672  centG    u16[262144] (512 KB, granule order)
    int* hist = (int*)d_ws;
    int* cursor = (int*)((char*)d_ws + 4096);
    int* offsets = (int*)((char*)d_ws + 8192);
    int* rowidx = (int*)((char*)d_ws + 16384);
    unsigned short* centG = (unsigned short*)((char*)d_ws + 540672);

    hipMemsetAsync(d_ws, 0, 8192, stream);    // zero hist + cursor

    k_hist<<<NROWS / 256, 256, 0, stream>>>(labels, hist);
    k_scan<<<1, CDIM, 0, stream>>>(hist, offsets, out);
    k_scatter<<<NROWS / 256, 256, 0, stream>>>(labels, offsets, cursor, rowidx);
    k_centroid<<<CDIM, 256, 0, stream>>>(emb, rowidx, offsets, centG);
    k_logits<<<NROWS / 256, 512, 0, stream>>>(emb, labels, centG, wp, out);
}